// Round 1
// baseline (2303.234 us; speedup 1.0000x reference)
//
#include <hip/hip_runtime.h>
#include <hip/hip_bf16.h>
#include <math.h>

#define HID 2048
#define NH 16
#define NKV 8
#define HD 128
#define SEQ 2048
#define EPS 1e-6f
#define SCALE 0.08838834764831845f  // 128^-0.5

// ---------------- wave helpers (wave64) ----------------
__device__ __forceinline__ float wave_reduce_sum(float v) {
#pragma unroll
    for (int off = 32; off > 0; off >>= 1) v += __shfl_xor(v, off);
    return v;
}
__device__ __forceinline__ float wave_reduce_max(float v) {
#pragma unroll
    for (int off = 32; off > 0; off >>= 1) v = fmaxf(v, __shfl_xor(v, off));
    return v;
}

// ---------------- 1. hidden RMSNorm ----------------
// one block per row, 256 threads, 8 floats/thread
__global__ __launch_bounds__(256) void rmsnorm_hid_kernel(
    const float* __restrict__ x, const float* __restrict__ w,
    float* __restrict__ out) {
    int row = blockIdx.x;
    int tid = threadIdx.x;
    const float* xr = x + (size_t)row * HID;
    float4 a = *(const float4*)(xr + tid * 4);
    float4 b = *(const float4*)(xr + 1024 + tid * 4);
    float ss = a.x * a.x + a.y * a.y + a.z * a.z + a.w * a.w +
               b.x * b.x + b.y * b.y + b.z * b.z + b.w * b.w;
    ss = wave_reduce_sum(ss);
    __shared__ float part[4];
    __shared__ float s_scale;
    if ((tid & 63) == 0) part[tid >> 6] = ss;
    __syncthreads();
    if (tid == 0) {
        float t = part[0] + part[1] + part[2] + part[3];
        s_scale = rsqrtf(t / (float)HID + EPS);
    }
    __syncthreads();
    float sc = s_scale;
    float4 wa = *(const float4*)(w + tid * 4);
    float4 wb = *(const float4*)(w + 1024 + tid * 4);
    float* orow = out + (size_t)row * HID;
    float4 oa = make_float4(a.x * sc * wa.x, a.y * sc * wa.y,
                            a.z * sc * wa.z, a.w * sc * wa.w);
    float4 ob = make_float4(b.x * sc * wb.x, b.y * sc * wb.y,
                            b.z * sc * wb.z, b.w * sc * wb.w);
    *(float4*)(orow + tid * 4) = oa;
    *(float4*)(orow + 1024 + tid * 4) = ob;
}

// ---------------- 2/5. C = A @ B^T  (A: MxK rowmajor, B: NxK rowmajor) ----------
// 64x64 tile, BK=16, 256 threads, 4x4 microtile.
// MODE 0: plain store to C0 (row stride N)
// MODE 1: qkv split-store: n<2048 -> C0 (q, stride 2048); n<3072 -> C1 (k, stride 1024); else C2 (v)
template <int MODE>
__global__ __launch_bounds__(256) void gemm_bt_kernel(
    const float* __restrict__ A, const float* __restrict__ B,
    float* __restrict__ C0, float* __restrict__ C1, float* __restrict__ C2,
    int M, int N, int K) {
    __shared__ float As[64][17];
    __shared__ float Bs[64][17];
    int tid = threadIdx.x;
    int m0 = blockIdx.y * 64;
    int n0 = blockIdx.x * 64;
    int lr = tid >> 2;          // 0..63
    int lc = (tid & 3) * 4;     // 0,4,8,12
    const float* Ap = A + (size_t)(m0 + lr) * K + lc;
    const float* Bp = B + (size_t)(n0 + lr) * K + lc;
    int tx = tid & 15, ty = tid >> 4;
    float acc[4][4] = {};
    for (int k0 = 0; k0 < K; k0 += 16) {
        float4 av = *(const float4*)(Ap + k0);
        float4 bv = *(const float4*)(Bp + k0);
        As[lr][lc] = av.x; As[lr][lc + 1] = av.y;
        As[lr][lc + 2] = av.z; As[lr][lc + 3] = av.w;
        Bs[lr][lc] = bv.x; Bs[lr][lc + 1] = bv.y;
        Bs[lr][lc + 2] = bv.z; Bs[lr][lc + 3] = bv.w;
        __syncthreads();
#pragma unroll
        for (int kk = 0; kk < 16; ++kk) {
            float a0 = As[ty * 4 + 0][kk];
            float a1 = As[ty * 4 + 1][kk];
            float a2 = As[ty * 4 + 2][kk];
            float a3 = As[ty * 4 + 3][kk];
            float b0 = Bs[tx * 4 + 0][kk];
            float b1 = Bs[tx * 4 + 1][kk];
            float b2 = Bs[tx * 4 + 2][kk];
            float b3 = Bs[tx * 4 + 3][kk];
            acc[0][0] = fmaf(a0, b0, acc[0][0]);
            acc[0][1] = fmaf(a0, b1, acc[0][1]);
            acc[0][2] = fmaf(a0, b2, acc[0][2]);
            acc[0][3] = fmaf(a0, b3, acc[0][3]);
            acc[1][0] = fmaf(a1, b0, acc[1][0]);
            acc[1][1] = fmaf(a1, b1, acc[1][1]);
            acc[1][2] = fmaf(a1, b2, acc[1][2]);
            acc[1][3] = fmaf(a1, b3, acc[1][3]);
            acc[2][0] = fmaf(a2, b0, acc[2][0]);
            acc[2][1] = fmaf(a2, b1, acc[2][1]);
            acc[2][2] = fmaf(a2, b2, acc[2][2]);
            acc[2][3] = fmaf(a2, b3, acc[2][3]);
            acc[3][0] = fmaf(a3, b0, acc[3][0]);
            acc[3][1] = fmaf(a3, b1, acc[3][1]);
            acc[3][2] = fmaf(a3, b2, acc[3][2]);
            acc[3][3] = fmaf(a3, b3, acc[3][3]);
        }
        __syncthreads();
    }
#pragma unroll
    for (int i = 0; i < 4; ++i) {
        int m = m0 + ty * 4 + i;
#pragma unroll
        for (int j = 0; j < 4; ++j) {
            int n = n0 + tx * 4 + j;
            float val = acc[i][j];
            if (MODE == 0) {
                C0[(size_t)m * N + n] = val;
            } else {
                if (n < NH * HD)
                    C0[(size_t)m * (NH * HD) + n] = val;
                else if (n < (NH + NKV) * HD)
                    C1[(size_t)m * (NKV * HD) + (n - NH * HD)] = val;
                else
                    C2[(size_t)m * (NKV * HD) + (n - (NH + NKV) * HD)] = val;
            }
        }
    }
}

// ---------------- 3. per-head q/k RMSNorm + RoPE (in place) ----------------
// grid (SEQ, NH+NKV), 128 threads
__global__ __launch_bounds__(128) void qknorm_rope_kernel(
    float* __restrict__ q, float* __restrict__ k,
    const float* __restrict__ qw, const float* __restrict__ kw,
    const int* __restrict__ pos) {
    int s = blockIdx.x;
    int hh = blockIdx.y;  // 0..NH-1 -> q head; NH..NH+NKV-1 -> k head
    int d = threadIdx.x;  // 0..127
    float* ptr;
    const float* w;
    if (hh < NH) {
        ptr = q + (size_t)s * (NH * HD) + hh * HD;
        w = qw;
    } else {
        ptr = k + (size_t)s * (NKV * HD) + (hh - NH) * HD;
        w = kw;
    }
    float x = ptr[d];
    float ss = wave_reduce_sum(x * x);
    __shared__ float part[2];
    if ((d & 63) == 0) part[d >> 6] = ss;
    __syncthreads();
    float tot = part[0] + part[1];
    float xn = x * rsqrtf(tot / (float)HD + EPS) * w[d];
    __shared__ float sh[HD];
    sh[d] = xn;
    __syncthreads();
    int j = d & 63;
    float inv = powf(10000.0f, -(float)(2 * j) * (1.0f / (float)HD));
    float fr = (float)pos[s] * inv;
    float sn, cs;
    sincosf(fr, &sn, &cs);
    float o;
    if (d < 64)
        o = xn * cs - sh[d + 64] * sn;   // x1*cos - x2*sin
    else
        o = xn * cs + sh[d - 64] * sn;   // x2*cos + x1*sin
    ptr[d] = o;
}

// ---------------- 4. causal GQA flash attention ----------------
// one wave per query row, 4 rows/block (256 threads), 64-key tiles.
// Single 64x128 LDS buffer reused for K (XOR-swizzled) then V (plain).
__global__ __launch_bounds__(256) void attn_kernel(
    const float* __restrict__ q, const float* __restrict__ k,
    const float* __restrict__ v, float* __restrict__ o) {
    __shared__ float buf[64][128];   // K tile (swizzled) then V tile (plain)
    __shared__ float qsh[4][128];
    __shared__ float psh[4][64];
    int tid = threadIdx.x;
    int w = tid >> 6, lane = tid & 63;
    int sbase = blockIdx.x * 4;
    int h = blockIdx.y;
    int kvh = h >> 1;  // rep = NH/NKV = 2
    int s = sbase + w;

    if (tid < 128) {
        int r = tid >> 5, c = (tid & 31) * 4;
        *(float4*)&qsh[r][c] =
            *(const float4*)(q + (size_t)(sbase + r) * (NH * HD) + h * HD + c);
    }

    float o0 = 0.f, o1 = 0.f, m_i = -1e30f, l_i = 0.f;
    int ntiles = (sbase >> 6) + 1;
    int r = tid >> 2, cg = tid & 3;

    for (int tt = 0; tt < ntiles; ++tt) {
        int t0 = tt * 64;
        const float* kp = k + (size_t)(t0 + r) * (NKV * HD) + kvh * HD;
        const float* vp = v + (size_t)(t0 + r) * (NKV * HD) + kvh * HD;
        int rx = r & 31;

        __syncthreads();  // previous PV reads done (also covers qsh on iter 0)
        // stage K tile, XOR-swizzled columns
#pragma unroll
        for (int jj = 0; jj < 8; ++jj) {
            int c = (cg + jj * 4) * 4;
            float4 k4 = *(const float4*)(kp + c);
            buf[r][(c + 0) ^ rx] = k4.x;
            buf[r][(c + 1) ^ rx] = k4.y;
            buf[r][(c + 2) ^ rx] = k4.z;
            buf[r][(c + 3) ^ rx] = k4.w;
        }
        __syncthreads();

        // scores: lane t computes q_row . k_t
        float acc = 0.f;
        int lx = lane & 31;
#pragma unroll 8
        for (int d = 0; d < 128; ++d)
            acc = fmaf(qsh[w][d], buf[lane][d ^ lx], acc);
        float sc = acc * SCALE;
        int kt = t0 + lane;
        if (kt > s) sc = -1e30f;

        float m_new = fmaxf(m_i, wave_reduce_max(sc));
        float p = __expf(sc - m_new);
        float sum = wave_reduce_sum(p);
        float alpha = __expf(m_i - m_new);
        l_i = l_i * alpha + sum;
        o0 *= alpha;
        o1 *= alpha;
        m_i = m_new;
        psh[w][lane] = p;
        __syncthreads();  // scores done with buf; psh visible

        // stage V tile (plain layout)
#pragma unroll
        for (int jj = 0; jj < 8; ++jj) {
            int c = (cg + jj * 4) * 4;
            float4 v4 = *(const float4*)(vp + c);
            buf[r][c + 0] = v4.x;
            buf[r][c + 1] = v4.y;
            buf[r][c + 2] = v4.z;
            buf[r][c + 3] = v4.w;
        }
        __syncthreads();

        // o += p . V  (lane owns dims lane and lane+64)
#pragma unroll 8
        for (int t = 0; t < 64; ++t) {
            float pt = psh[w][t];
            o0 = fmaf(pt, buf[t][lane], o0);
            o1 = fmaf(pt, buf[t][lane + 64], o1);
        }
    }
    float inv_l = 1.0f / l_i;
    float* op = o + (size_t)s * (NH * HD) + h * HD;
    op[lane] = o0 * inv_l;
    op[lane + 64] = o1 * inv_l;
}

// ---------------- launch ----------------
extern "C" void kernel_launch(void* const* d_in, const int* in_sizes, int n_in,
                              void* d_out, int out_size, void* d_ws, size_t ws_size,
                              hipStream_t stream) {
    const int* positions   = (const int*)d_in[0];
    const float* hidden    = (const float*)d_in[1];
    const float* ln_w      = (const float*)d_in[2];
    const float* w_qkv     = (const float*)d_in[3];
    const float* w_o       = (const float*)d_in[4];
    const float* q_norm_w  = (const float*)d_in[5];
    const float* k_norm_w  = (const float*)d_in[6];
    float* out = (float*)d_out;

    float* ws = (float*)d_ws;
    float* hn = ws;                       // SEQ*HID floats; reused as attn output
    float* qb = ws + (size_t)4 * 1024 * 1024;   // SEQ*NH*HD
    float* kb = ws + (size_t)8 * 1024 * 1024;   // SEQ*NKV*HD
    float* vb = ws + (size_t)10 * 1024 * 1024;  // SEQ*NKV*HD

    rmsnorm_hid_kernel<<<SEQ, 256, 0, stream>>>(hidden, ln_w, hn);
    gemm_bt_kernel<1><<<dim3(64, 32), 256, 0, stream>>>(
        hn, w_qkv, qb, kb, vb, SEQ, (NH + 2 * NKV) * HD, HID);
    qknorm_rope_kernel<<<dim3(SEQ, NH + NKV), 128, 0, stream>>>(
        qb, kb, q_norm_w, k_norm_w, positions);
    attn_kernel<<<dim3(SEQ / 4, NH), 256, 0, stream>>>(qb, kb, vb, hn);
    gemm_bt_kernel<0><<<dim3(32, 32), 256, 0, stream>>>(
        hn, w_o, out, nullptr, nullptr, SEQ, NH * HD, HID);
}

// Round 2
// 1321.022 us; speedup vs baseline: 1.7435x; 1.7435x over previous
//
#include <hip/hip_runtime.h>
#include <hip/hip_bf16.h>
#include <math.h>

#define HID 2048
#define NH 16
#define NKV 8
#define HD 128
#define SEQ 2048
#define EPS 1e-6f
#define SCALE 0.08838834764831845f  // 128^-0.5

typedef __attribute__((ext_vector_type(8))) short bf8_t;   // 8 bf16 (4 VGPRs)
typedef __attribute__((ext_vector_type(4))) float f4_t;    // 4 fp32

__device__ __forceinline__ short f2bf(float f) {
    union { __hip_bfloat16 h; short s; } u;
    u.h = __float2bfloat16(f);
    return u.s;
}
__device__ __forceinline__ bf8_t pack8(const float4& a, const float4& b) {
    bf8_t r;
    r[0] = f2bf(a.x); r[1] = f2bf(a.y); r[2] = f2bf(a.z); r[3] = f2bf(a.w);
    r[4] = f2bf(b.x); r[5] = f2bf(b.y); r[6] = f2bf(b.z); r[7] = f2bf(b.w);
    return r;
}

// ---------------- wave helpers (wave64) ----------------
__device__ __forceinline__ float wave_reduce_sum(float v) {
#pragma unroll
    for (int off = 32; off > 0; off >>= 1) v += __shfl_xor(v, off);
    return v;
}

// ---------------- 1. hidden RMSNorm ----------------
__global__ __launch_bounds__(256) void rmsnorm_hid_kernel(
    const float* __restrict__ x, const float* __restrict__ w,
    float* __restrict__ out) {
    int row = blockIdx.x;
    int tid = threadIdx.x;
    const float* xr = x + (size_t)row * HID;
    float4 a = *(const float4*)(xr + tid * 4);
    float4 b = *(const float4*)(xr + 1024 + tid * 4);
    float ss = a.x * a.x + a.y * a.y + a.z * a.z + a.w * a.w +
               b.x * b.x + b.y * b.y + b.z * b.z + b.w * b.w;
    ss = wave_reduce_sum(ss);
    __shared__ float part[4];
    __shared__ float s_scale;
    if ((tid & 63) == 0) part[tid >> 6] = ss;
    __syncthreads();
    if (tid == 0) {
        float t = part[0] + part[1] + part[2] + part[3];
        s_scale = rsqrtf(t / (float)HID + EPS);
    }
    __syncthreads();
    float sc = s_scale;
    float4 wa = *(const float4*)(w + tid * 4);
    float4 wb = *(const float4*)(w + 1024 + tid * 4);
    float* orow = out + (size_t)row * HID;
    float4 oa = make_float4(a.x * sc * wa.x, a.y * sc * wa.y,
                            a.z * sc * wa.z, a.w * sc * wa.w);
    float4 ob = make_float4(b.x * sc * wb.x, b.y * sc * wb.y,
                            b.z * sc * wb.z, b.w * sc * wb.w);
    *(float4*)(orow + tid * 4) = oa;
    *(float4*)(orow + 1024 + tid * 4) = ob;
}

// ---------------- 2/5. C = A @ B^T  (A: MxK rowmajor, B: NxK rowmajor) ----------
// MODE 0: plain store to C0 (row stride N)
// MODE 1: qkv split: n<2048 -> C0 (q); n<3072 -> C1 (k); else -> C2 = v TRANSPOSED
//         (v^T[dim][seq], row stride M) so attention can read V key-major.
template <int MODE>
__global__ __launch_bounds__(256) void gemm_bt_kernel(
    const float* __restrict__ A, const float* __restrict__ B,
    float* __restrict__ C0, float* __restrict__ C1, float* __restrict__ C2,
    int M, int N, int K) {
    __shared__ float As[64][17];
    __shared__ float Bs[64][17];
    int tid = threadIdx.x;
    int m0 = blockIdx.y * 64;
    int n0 = blockIdx.x * 64;
    int lr = tid >> 2;
    int lc = (tid & 3) * 4;
    const float* Ap = A + (size_t)(m0 + lr) * K + lc;
    const float* Bp = B + (size_t)(n0 + lr) * K + lc;
    int tx = tid & 15, ty = tid >> 4;
    float acc[4][4] = {};
    for (int k0 = 0; k0 < K; k0 += 16) {
        float4 av = *(const float4*)(Ap + k0);
        float4 bv = *(const float4*)(Bp + k0);
        As[lr][lc] = av.x; As[lr][lc + 1] = av.y;
        As[lr][lc + 2] = av.z; As[lr][lc + 3] = av.w;
        Bs[lr][lc] = bv.x; Bs[lr][lc + 1] = bv.y;
        Bs[lr][lc + 2] = bv.z; Bs[lr][lc + 3] = bv.w;
        __syncthreads();
#pragma unroll
        for (int kk = 0; kk < 16; ++kk) {
            float a0 = As[ty * 4 + 0][kk];
            float a1 = As[ty * 4 + 1][kk];
            float a2 = As[ty * 4 + 2][kk];
            float a3 = As[ty * 4 + 3][kk];
            float b0 = Bs[tx * 4 + 0][kk];
            float b1 = Bs[tx * 4 + 1][kk];
            float b2 = Bs[tx * 4 + 2][kk];
            float b3 = Bs[tx * 4 + 3][kk];
            acc[0][0] = fmaf(a0, b0, acc[0][0]);
            acc[0][1] = fmaf(a0, b1, acc[0][1]);
            acc[0][2] = fmaf(a0, b2, acc[0][2]);
            acc[0][3] = fmaf(a0, b3, acc[0][3]);
            acc[1][0] = fmaf(a1, b0, acc[1][0]);
            acc[1][1] = fmaf(a1, b1, acc[1][1]);
            acc[1][2] = fmaf(a1, b2, acc[1][2]);
            acc[1][3] = fmaf(a1, b3, acc[1][3]);
            acc[2][0] = fmaf(a2, b0, acc[2][0]);
            acc[2][1] = fmaf(a2, b1, acc[2][1]);
            acc[2][2] = fmaf(a2, b2, acc[2][2]);
            acc[2][3] = fmaf(a2, b3, acc[2][3]);
            acc[3][0] = fmaf(a3, b0, acc[3][0]);
            acc[3][1] = fmaf(a3, b1, acc[3][1]);
            acc[3][2] = fmaf(a3, b2, acc[3][2]);
            acc[3][3] = fmaf(a3, b3, acc[3][3]);
        }
        __syncthreads();
    }
#pragma unroll
    for (int i = 0; i < 4; ++i) {
        int m = m0 + ty * 4 + i;
#pragma unroll
        for (int j = 0; j < 4; ++j) {
            int n = n0 + tx * 4 + j;
            float val = acc[i][j];
            if (MODE == 0) {
                C0[(size_t)m * N + n] = val;
            } else {
                if (n < NH * HD)
                    C0[(size_t)m * (NH * HD) + n] = val;
                else if (n < (NH + NKV) * HD)
                    C1[(size_t)m * (NKV * HD) + (n - NH * HD)] = val;
                else
                    C2[(size_t)(n - (NH + NKV) * HD) * M + m] = val;  // v^T
            }
        }
    }
}

// ---------------- 3. per-head q/k RMSNorm + RoPE (in place, fp32) ----------------
__global__ __launch_bounds__(128) void qknorm_rope_kernel(
    float* __restrict__ q, float* __restrict__ k,
    const float* __restrict__ qw, const float* __restrict__ kw,
    const int* __restrict__ pos) {
    int s = blockIdx.x;
    int hh = blockIdx.y;
    int d = threadIdx.x;
    float* ptr;
    const float* w;
    if (hh < NH) {
        ptr = q + (size_t)s * (NH * HD) + hh * HD;
        w = qw;
    } else {
        ptr = k + (size_t)s * (NKV * HD) + (hh - NH) * HD;
        w = kw;
    }
    float x = ptr[d];
    float ss = wave_reduce_sum(x * x);
    __shared__ float part[2];
    if ((d & 63) == 0) part[d >> 6] = ss;
    __syncthreads();
    float tot = part[0] + part[1];
    float xn = x * rsqrtf(tot / (float)HD + EPS) * w[d];
    __shared__ float sh[HD];
    sh[d] = xn;
    __syncthreads();
    int j = d & 63;
    float inv = powf(10000.0f, -(float)(2 * j) * (1.0f / (float)HD));
    float fr = (float)pos[s] * inv;
    float sn, cs;
    sincosf(fr, &sn, &cs);
    float o;
    if (d < 64)
        o = xn * cs - sh[d + 64] * sn;
    else
        o = xn * cs + sh[d - 64] * sn;
    ptr[d] = o;
}

// ---------------- 4. MFMA flash attention (bf16, causal GQA) ----------------
// Block: 256 threads = 4 waves; 64 q-rows/block (16 per wave); 64-key tiles.
// K staged [key][dim] bf16 (+8 pad), V^T staged [dim][key] bf16 (+8 pad).
// S = Q K^T and O += P V both via mfma_f32_16x16x32_bf16.
__global__ __launch_bounds__(256) void attn_mfma_kernel(
    const float* __restrict__ q, const float* __restrict__ k,
    const float* __restrict__ vt, float* __restrict__ o) {
    __shared__ __align__(16) short kbuf[64][136];
    __shared__ __align__(16) short vbuf[128][72];
    __shared__ __align__(16) short psh[4][16][72];

    int tid = threadIdx.x;
    int wv = tid >> 6, lane = tid & 63;
    int n = lane & 15, qd = lane >> 4;
    int qb = (int)gridDim.x - 1 - (int)blockIdx.x;  // heavy blocks dispatched first
    int h = blockIdx.y, kvh = h >> 1;
    int qbase = qb * 64;

    // Q A-fragments: A[m=lane&15 -> q-row][k=qd*8+j + ks*32]
    bf8_t qf[4];
    {
        const float* qp = q + (size_t)(qbase + wv * 16 + n) * (NH * HD) + h * HD + qd * 8;
#pragma unroll
        for (int ks = 0; ks < 4; ++ks) {
            float4 a = *(const float4*)(qp + ks * 32);
            float4 b = *(const float4*)(qp + ks * 32 + 4);
            qf[ks] = pack8(a, b);
        }
    }

    f4_t of[8];
#pragma unroll
    for (int i = 0; i < 8; ++i) of[i] = (f4_t){0.f, 0.f, 0.f, 0.f};
    float m_i[4] = {-1e30f, -1e30f, -1e30f, -1e30f};
    float l_p[4] = {0.f, 0.f, 0.f, 0.f};

    for (int tt = 0; tt <= qb; ++tt) {
        int t0 = tt * 64;
        __syncthreads();  // prior tile's LDS reads done before overwrite
        // stage K tile [key][dim]
#pragma unroll
        for (int it = 0; it < 4; ++it) {
            int f8 = tid + it * 256;
            int key = f8 >> 4, d0 = (f8 & 15) * 8;
            const float* kp = k + (size_t)(t0 + key) * (NKV * HD) + kvh * HD + d0;
            float4 a = *(const float4*)kp;
            float4 b = *(const float4*)(kp + 4);
            *(bf8_t*)&kbuf[key][d0] = pack8(a, b);
        }
        // stage V^T tile [dim][key]
#pragma unroll
        for (int it = 0; it < 4; ++it) {
            int f8 = tid + it * 256;
            int dim = f8 >> 3, c0 = (f8 & 7) * 8;
            const float* vp = vt + (size_t)(kvh * HD + dim) * SEQ + t0 + c0;
            float4 a = *(const float4*)vp;
            float4 b = *(const float4*)(vp + 4);
            *(bf8_t*)&vbuf[dim][c0] = pack8(a, b);
        }
        __syncthreads();

        // S = Q K^T : 4 key-blocks x 4 k-steps
        f4_t sc[4];
#pragma unroll
        for (int kb = 0; kb < 4; ++kb) sc[kb] = (f4_t){0.f, 0.f, 0.f, 0.f};
#pragma unroll
        for (int kb = 0; kb < 4; ++kb)
#pragma unroll
            for (int ks = 0; ks < 4; ++ks) {
                bf8_t kf = *(const bf8_t*)&kbuf[kb * 16 + n][ks * 32 + qd * 8];
                sc[kb] = __builtin_amdgcn_mfma_f32_16x16x32_bf16(qf[ks], kf, sc[kb], 0, 0, 0);
            }

        // scale + causal mask (diagonal tile only)
        bool diag = (tt == qb);
#pragma unroll
        for (int kb = 0; kb < 4; ++kb)
#pragma unroll
            for (int r = 0; r < 4; ++r) {
                float s = sc[kb][r] * SCALE;
                if (diag && (kb * 16 + n > wv * 16 + qd * 4 + r)) s = -1e30f;
                sc[kb][r] = s;
            }

        // online softmax: row max across 16 lanes (cols), rows live in (qd, reg)
        float al[4];
#pragma unroll
        for (int r = 0; r < 4; ++r) {
            float mx = fmaxf(fmaxf(sc[0][r], sc[1][r]), fmaxf(sc[2][r], sc[3][r]));
#pragma unroll
            for (int off = 1; off < 16; off <<= 1) mx = fmaxf(mx, __shfl_xor(mx, off));
            float mnew = fmaxf(m_i[r], mx);
            al[r] = __expf(m_i[r] - mnew);
            m_i[r] = mnew;
        }
#pragma unroll
        for (int r = 0; r < 4; ++r) {
            float lsum = 0.f;
#pragma unroll
            for (int kb = 0; kb < 4; ++kb) {
                float p = __expf(sc[kb][r] - m_i[r]);
                psh[wv][qd * 4 + r][kb * 16 + n] = f2bf(p);
                lsum += p;
            }
            l_p[r] = l_p[r] * al[r] + lsum;  // cross-lane reduce deferred to end
#pragma unroll
            for (int nb = 0; nb < 8; ++nb) of[nb][r] *= al[r];
        }
        __syncthreads();  // psh C-layout -> A-layout round trip

        // O += P V : P A-frags from psh, V B-frags from vbuf (V^T, key-contiguous)
#pragma unroll
        for (int ks2 = 0; ks2 < 2; ++ks2) {
            bf8_t pf = *(const bf8_t*)&psh[wv][n][ks2 * 32 + qd * 8];
#pragma unroll
            for (int nb = 0; nb < 8; ++nb) {
                bf8_t vf = *(const bf8_t*)&vbuf[nb * 16 + n][ks2 * 32 + qd * 8];
                of[nb] = __builtin_amdgcn_mfma_f32_16x16x32_bf16(pf, vf, of[nb], 0, 0, 0);
            }
        }
    }

    // final: cross-lane l reduction, normalize, store
    float inv[4];
#pragma unroll
    for (int r = 0; r < 4; ++r) {
        float l = l_p[r];
#pragma unroll
        for (int off = 1; off < 16; off <<= 1) l += __shfl_xor(l, off);
        inv[r] = 1.0f / l;
    }
#pragma unroll
    for (int nb = 0; nb < 8; ++nb)
#pragma unroll
        for (int r = 0; r < 4; ++r) {
            int row = qbase + wv * 16 + qd * 4 + r;
            o[(size_t)row * (NH * HD) + h * HD + nb * 16 + n] = of[nb][r] * inv[r];
        }
}

// ---------------- launch ----------------
extern "C" void kernel_launch(void* const* d_in, const int* in_sizes, int n_in,
                              void* d_out, int out_size, void* d_ws, size_t ws_size,
                              hipStream_t stream) {
    const int* positions   = (const int*)d_in[0];
    const float* hidden    = (const float*)d_in[1];
    const float* ln_w      = (const float*)d_in[2];
    const float* w_qkv     = (const float*)d_in[3];
    const float* w_o       = (const float*)d_in[4];
    const float* q_norm_w  = (const float*)d_in[5];
    const float* k_norm_w  = (const float*)d_in[6];
    float* out = (float*)d_out;

    float* ws = (float*)d_ws;
    float* hn = ws;                             // SEQ*HID; reused as attn output
    float* qb = ws + (size_t)4 * 1024 * 1024;   // SEQ*NH*HD
    float* kb = ws + (size_t)8 * 1024 * 1024;   // SEQ*NKV*HD
    float* vt = ws + (size_t)10 * 1024 * 1024;  // NKV*HD x SEQ (v transposed)

    rmsnorm_hid_kernel<<<SEQ, 256, 0, stream>>>(hidden, ln_w, hn);
    gemm_bt_kernel<1><<<dim3(64, 32), 256, 0, stream>>>(
        hn, w_qkv, qb, kb, vt, SEQ, (NH + 2 * NKV) * HD, HID);
    qknorm_rope_kernel<<<dim3(SEQ, NH + NKV), 128, 0, stream>>>(
        qb, kb, q_norm_w, k_norm_w, positions);
    attn_mfma_kernel<<<dim3(32, NH), 256, 0, stream>>>(qb, kb, vt, hn);
    gemm_bt_kernel<0><<<dim3(32, 32), 256, 0, stream>>>(
        hn, w_o, out, nullptr, nullptr, SEQ, NH * HD, HID);
}

// Round 3
// 396.717 us; speedup vs baseline: 5.8057x; 3.3299x over previous
//
#include <hip/hip_runtime.h>
#include <hip/hip_bf16.h>
#include <math.h>

#define HID 2048
#define NH 16
#define NKV 8
#define HD 128
#define SEQ 2048
#define EPS 1e-6f
#define SCALE 0.08838834764831845f  // 128^-0.5

typedef __attribute__((ext_vector_type(8))) short bf8_t;   // 8 bf16 (4 VGPRs)
typedef __attribute__((ext_vector_type(4))) float f4_t;    // 4 fp32

__device__ __forceinline__ short f2bf(float f) {
    union { __hip_bfloat16 h; short s; } u;
    u.h = __float2bfloat16(f);
    return u.s;
}
__device__ __forceinline__ float bf2f(short s) {
    union { short s; __hip_bfloat16 h; } u;
    u.s = s;
    return __bfloat162float(u.h);
}
__device__ __forceinline__ bf8_t pack8(const float4& a, const float4& b) {
    bf8_t r;
    r[0] = f2bf(a.x); r[1] = f2bf(a.y); r[2] = f2bf(a.z); r[3] = f2bf(a.w);
    r[4] = f2bf(b.x); r[5] = f2bf(b.y); r[6] = f2bf(b.z); r[7] = f2bf(b.w);
    return r;
}
// async global->LDS, 16 B per lane; lds base must be wave-uniform
__device__ __forceinline__ void gload16(const short* g, short* l) {
    __builtin_amdgcn_global_load_lds(
        (const __attribute__((address_space(1))) unsigned int*)g,
        (__attribute__((address_space(3))) unsigned int*)l, 16, 0, 0);
}

__device__ __forceinline__ float wave_reduce_sum(float v) {
#pragma unroll
    for (int off = 32; off > 0; off >>= 1) v += __shfl_xor(v, off);
    return v;
}

// ---------------- fp32 -> bf16 convert (weights) ----------------
__global__ __launch_bounds__(256) void f2bf_kernel(
    const float* __restrict__ src, short* __restrict__ dst, int n8) {
    int i = blockIdx.x * 256 + threadIdx.x;
    if (i < n8) {
        float4 a = *(const float4*)(src + (size_t)i * 8);
        float4 b = *(const float4*)(src + (size_t)i * 8 + 4);
        *(bf8_t*)(dst + (size_t)i * 8) = pack8(a, b);
    }
}

// ---------------- 1. hidden RMSNorm (fp32 in, bf16 out) ----------------
__global__ __launch_bounds__(256) void rmsnorm_hid_kernel(
    const float* __restrict__ x, const float* __restrict__ w,
    short* __restrict__ out) {
    int row = blockIdx.x;
    int tid = threadIdx.x;
    const float* xr = x + (size_t)row * HID;
    float4 a = *(const float4*)(xr + tid * 8);
    float4 b = *(const float4*)(xr + tid * 8 + 4);
    float ss = a.x * a.x + a.y * a.y + a.z * a.z + a.w * a.w +
               b.x * b.x + b.y * b.y + b.z * b.z + b.w * b.w;
    ss = wave_reduce_sum(ss);
    __shared__ float part[4];
    __shared__ float s_scale;
    if ((tid & 63) == 0) part[tid >> 6] = ss;
    __syncthreads();
    if (tid == 0) {
        float t = part[0] + part[1] + part[2] + part[3];
        s_scale = rsqrtf(t / (float)HID + EPS);
    }
    __syncthreads();
    float sc = s_scale;
    float4 wa = *(const float4*)(w + tid * 8);
    float4 wb = *(const float4*)(w + tid * 8 + 4);
    float4 oa = make_float4(a.x * sc * wa.x, a.y * sc * wa.y,
                            a.z * sc * wa.z, a.w * sc * wa.w);
    float4 ob = make_float4(b.x * sc * wb.x, b.y * sc * wb.y,
                            b.z * sc * wb.z, b.w * sc * wb.w);
    *(bf8_t*)(out + (size_t)row * HID + tid * 8) = pack8(oa, ob);
}

// ---------------- 2/5. bf16 MFMA GEMM: C = A @ B^T ----------------
// A: MxK bf16 rowmajor, B: NxK bf16 rowmajor. 128x128 tile, BK=32,
// 4 waves (2x2), each 64x64 = 4x4 mfma_f32_16x16x32_bf16.
// Staging via global_load_lds (16 B/lane); unpadded LDS with k-chunk swizzle
// slot = (chunk + (row>>1)) & 3  -> every 16-lane b128 group is 2-way (free).
// MODE 0: store fp32 to Cf (row stride N)
// MODE 1: qkv split: n<2048 -> Q bf16; n<3072 -> Kp bf16; else VT bf16 transposed
template <int MODE>
__global__ __launch_bounds__(256) void gemm_mfma_kernel(
    const short* __restrict__ A, const short* __restrict__ B,
    float* __restrict__ Cf, short* __restrict__ Q, short* __restrict__ Kp,
    short* __restrict__ VT, int M, int N, int K) {
    __shared__ short As[128][32];
    __shared__ short Bs[128][32];
    int tid = threadIdx.x;
    int wv = tid >> 6, lane = tid & 63;
    int n16 = lane & 15, qd = lane >> 4;
    int m0 = blockIdx.y * 128, n0 = blockIdx.x * 128;
    int wm = (wv >> 1) * 64, wn = (wv & 1) * 64;
    int srow = lane >> 2;   // 0..15 within a 16-row chunk
    int sslot = lane & 3;

    f4_t acc[4][4];
#pragma unroll
    for (int i = 0; i < 4; ++i)
#pragma unroll
        for (int j = 0; j < 4; ++j) acc[i][j] = (f4_t){0.f, 0.f, 0.f, 0.f};

    for (int k0 = 0; k0 < K; k0 += 32) {
        __syncthreads();  // prior frags consumed
#pragma unroll
        for (int half = 0; half < 2; ++half) {
            int rb = wv * 32 + half * 16;
            int row = rb + srow;
            int c = (sslot - (row >> 1)) & 3;   // global chunk landing in slot sslot
            gload16(A + (size_t)(m0 + row) * K + k0 + c * 8, &As[rb][0]);
            gload16(B + (size_t)(n0 + row) * K + k0 + c * 8, &Bs[rb][0]);
        }
        __syncthreads();  // drains vmcnt -> LDS visible

        bf8_t af[4], bf[4];
#pragma unroll
        for (int t = 0; t < 4; ++t) {
            int ar = wm + t * 16 + n16;
            af[t] = *(const bf8_t*)&As[ar][((qd + (ar >> 1)) & 3) * 8];
            int br = wn + t * 16 + n16;
            bf[t] = *(const bf8_t*)&Bs[br][((qd + (br >> 1)) & 3) * 8];
        }
#pragma unroll
        for (int mt = 0; mt < 4; ++mt)
#pragma unroll
            for (int nt = 0; nt < 4; ++nt)
                acc[mt][nt] = __builtin_amdgcn_mfma_f32_16x16x32_bf16(
                    af[mt], bf[nt], acc[mt][nt], 0, 0, 0);
    }

    // epilogue: C row = qd*4+r, col = n16 within each 16x16 tile
#pragma unroll
    for (int mt = 0; mt < 4; ++mt)
#pragma unroll
        for (int nt = 0; nt < 4; ++nt)
#pragma unroll
            for (int r = 0; r < 4; ++r) {
                int gm = m0 + wm + mt * 16 + qd * 4 + r;
                int gn = n0 + wn + nt * 16 + n16;
                float v = acc[mt][nt][r];
                if (MODE == 0) {
                    Cf[(size_t)gm * N + gn] = v;
                } else {
                    if (gn < NH * HD)
                        Q[(size_t)gm * (NH * HD) + gn] = f2bf(v);
                    else if (gn < (NH + NKV) * HD)
                        Kp[(size_t)gm * (NKV * HD) + (gn - NH * HD)] = f2bf(v);
                    else
                        VT[(size_t)(gn - (NH + NKV) * HD) * M + gm] = f2bf(v);
                }
            }
}

// ---------------- 3. per-head q/k RMSNorm + RoPE (bf16, in place) ----------------
__global__ __launch_bounds__(128) void qknorm_rope_kernel(
    short* __restrict__ q, short* __restrict__ k,
    const float* __restrict__ qw, const float* __restrict__ kw,
    const int* __restrict__ pos) {
    int s = blockIdx.x;
    int hh = blockIdx.y;
    int d = threadIdx.x;
    short* ptr;
    const float* w;
    if (hh < NH) {
        ptr = q + (size_t)s * (NH * HD) + hh * HD;
        w = qw;
    } else {
        ptr = k + (size_t)s * (NKV * HD) + (hh - NH) * HD;
        w = kw;
    }
    float x = bf2f(ptr[d]);
    float ss = wave_reduce_sum(x * x);
    __shared__ float part[2];
    if ((d & 63) == 0) part[d >> 6] = ss;
    __syncthreads();
    float tot = part[0] + part[1];
    float xn = x * rsqrtf(tot / (float)HD + EPS) * w[d];
    __shared__ float sh[HD];
    sh[d] = xn;
    __syncthreads();
    int j = d & 63;
    float inv = powf(10000.0f, -(float)(2 * j) * (1.0f / (float)HD));
    float fr = (float)pos[s] * inv;
    float sn, cs;
    sincosf(fr, &sn, &cs);
    float o;
    if (d < 64)
        o = xn * cs - sh[d + 64] * sn;
    else
        o = xn * cs + sh[d - 64] * sn;
    ptr[d] = f2bf(o);
}

// ---------------- 4. MFMA flash attention (bf16 in/out, causal GQA) -------------
__global__ __launch_bounds__(256) void attn_mfma_kernel(
    const short* __restrict__ q, const short* __restrict__ k,
    const short* __restrict__ vt, short* __restrict__ o) {
    __shared__ __align__(16) short kbuf[64][136];
    __shared__ __align__(16) short vbuf[128][72];
    __shared__ __align__(16) short psh[4][16][72];

    int tid = threadIdx.x;
    int wv = tid >> 6, lane = tid & 63;
    int n = lane & 15, qd = lane >> 4;
    int qb = (int)gridDim.x - 1 - (int)blockIdx.x;  // heavy blocks first
    int h = blockIdx.y, kvh = h >> 1;
    int qbase = qb * 64;

    bf8_t qf[4];
    {
        const short* qp = q + (size_t)(qbase + wv * 16 + n) * (NH * HD) + h * HD + qd * 8;
#pragma unroll
        for (int ks = 0; ks < 4; ++ks) qf[ks] = *(const bf8_t*)(qp + ks * 32);
    }

    f4_t of[8];
#pragma unroll
    for (int i = 0; i < 8; ++i) of[i] = (f4_t){0.f, 0.f, 0.f, 0.f};
    float m_i[4] = {-1e30f, -1e30f, -1e30f, -1e30f};
    float l_p[4] = {0.f, 0.f, 0.f, 0.f};

    for (int tt = 0; tt <= qb; ++tt) {
        int t0 = tt * 64;
        __syncthreads();
#pragma unroll
        for (int it = 0; it < 4; ++it) {
            int f8 = tid + it * 256;
            int key = f8 >> 4, d0 = (f8 & 15) * 8;
            *(bf8_t*)&kbuf[key][d0] =
                *(const bf8_t*)(k + (size_t)(t0 + key) * (NKV * HD) + kvh * HD + d0);
        }
#pragma unroll
        for (int it = 0; it < 4; ++it) {
            int f8 = tid + it * 256;
            int dim = f8 >> 3, c0 = (f8 & 7) * 8;
            *(bf8_t*)&vbuf[dim][c0] =
                *(const bf8_t*)(vt + (size_t)(kvh * HD + dim) * SEQ + t0 + c0);
        }
        __syncthreads();

        f4_t sc[4];
#pragma unroll
        for (int kb = 0; kb < 4; ++kb) sc[kb] = (f4_t){0.f, 0.f, 0.f, 0.f};
#pragma unroll
        for (int kb = 0; kb < 4; ++kb)
#pragma unroll
            for (int ks = 0; ks < 4; ++ks) {
                bf8_t kf = *(const bf8_t*)&kbuf[kb * 16 + n][ks * 32 + qd * 8];
                sc[kb] = __builtin_amdgcn_mfma_f32_16x16x32_bf16(qf[ks], kf, sc[kb], 0, 0, 0);
            }

        bool diag = (tt == qb);
#pragma unroll
        for (int kb = 0; kb < 4; ++kb)
#pragma unroll
            for (int r = 0; r < 4; ++r) {
                float s = sc[kb][r] * SCALE;
                if (diag && (kb * 16 + n > wv * 16 + qd * 4 + r)) s = -1e30f;
                sc[kb][r] = s;
            }

        float al[4];
#pragma unroll
        for (int r = 0; r < 4; ++r) {
            float mx = fmaxf(fmaxf(sc[0][r], sc[1][r]), fmaxf(sc[2][r], sc[3][r]));
#pragma unroll
            for (int off = 1; off < 16; off <<= 1) mx = fmaxf(mx, __shfl_xor(mx, off));
            float mnew = fmaxf(m_i[r], mx);
            al[r] = __expf(m_i[r] - mnew);
            m_i[r] = mnew;
        }
#pragma unroll
        for (int r = 0; r < 4; ++r) {
            float lsum = 0.f;
#pragma unroll
            for (int kb = 0; kb < 4; ++kb) {
                float p = __expf(sc[kb][r] - m_i[r]);
                psh[wv][qd * 4 + r][kb * 16 + n] = f2bf(p);
                lsum += p;
            }
            l_p[r] = l_p[r] * al[r] + lsum;
#pragma unroll
            for (int nb = 0; nb < 8; ++nb) of[nb][r] *= al[r];
        }
        __syncthreads();

#pragma unroll
        for (int ks2 = 0; ks2 < 2; ++ks2) {
            bf8_t pf = *(const bf8_t*)&psh[wv][n][ks2 * 32 + qd * 8];
#pragma unroll
            for (int nb = 0; nb < 8; ++nb) {
                bf8_t vf = *(const bf8_t*)&vbuf[nb * 16 + n][ks2 * 32 + qd * 8];
                of[nb] = __builtin_amdgcn_mfma_f32_16x16x32_bf16(pf, vf, of[nb], 0, 0, 0);
            }
        }
    }

    float inv[4];
#pragma unroll
    for (int r = 0; r < 4; ++r) {
        float l = l_p[r];
#pragma unroll
        for (int off = 1; off < 16; off <<= 1) l += __shfl_xor(l, off);
        inv[r] = 1.0f / l;
    }
#pragma unroll
    for (int nb = 0; nb < 8; ++nb)
#pragma unroll
        for (int r = 0; r < 4; ++r) {
            int row = qbase + wv * 16 + qd * 4 + r;
            o[(size_t)row * (NH * HD) + h * HD + nb * 16 + n] = f2bf(of[nb][r] * inv[r]);
        }
}

// ---------------- launch ----------------
extern "C" void kernel_launch(void* const* d_in, const int* in_sizes, int n_in,
                              void* d_out, int out_size, void* d_ws, size_t ws_size,
                              hipStream_t stream) {
    const int* positions   = (const int*)d_in[0];
    const float* hidden    = (const float*)d_in[1];
    const float* ln_w      = (const float*)d_in[2];
    const float* w_qkv     = (const float*)d_in[3];
    const float* w_o       = (const float*)d_in[4];
    const float* q_norm_w  = (const float*)d_in[5];
    const float* k_norm_w  = (const float*)d_in[6];
    float* out = (float*)d_out;

    char* base = (char*)d_ws;
    short* hnb = (short*)(base);                        // 8 MB: hn bf16, later attn-out bf16
    short* wqb = (short*)(base + ((size_t)8 << 20));    // 16 MB: w_qkv bf16
    short* wob = (short*)(base + ((size_t)24 << 20));   // 8 MB: w_o bf16
    short* qbf = (short*)(base + ((size_t)32 << 20));   // 8 MB: q bf16 (rope in place)
    short* kbf = (short*)(base + ((size_t)40 << 20));   // 4 MB: k bf16 (rope in place)
    short* vtb = (short*)(base + ((size_t)44 << 20));   // 4 MB: v^T bf16

    f2bf_kernel<<<4096, 256, 0, stream>>>(w_qkv, wqb, (NH + 2 * NKV) * HD * HID / 8);
    f2bf_kernel<<<2048, 256, 0, stream>>>(w_o, wob, HID * NH * HD / 8);
    rmsnorm_hid_kernel<<<SEQ, 256, 0, stream>>>(hidden, ln_w, hnb);
    gemm_mfma_kernel<1><<<dim3(32, 16), 256, 0, stream>>>(
        hnb, wqb, nullptr, qbf, kbf, vtb, SEQ, (NH + 2 * NKV) * HD, HID);
    qknorm_rope_kernel<<<dim3(SEQ, NH + NKV), 128, 0, stream>>>(
        qbf, kbf, q_norm_w, k_norm_w, positions);
    attn_mfma_kernel<<<dim3(32, NH), 256, 0, stream>>>(qbf, kbf, vtb, hnb);
    gemm_mfma_kernel<0><<<dim3(16, 16), 256, 0, stream>>>(
        hnb, wob, out, nullptr, nullptr, nullptr, SEQ, NH * HD, HID);
}

// Round 4
// 332.409 us; speedup vs baseline: 6.9289x; 1.1935x over previous
//
#include <hip/hip_runtime.h>
#include <hip/hip_bf16.h>
#include <math.h>

#define HID 2048
#define NH 16
#define NKV 8
#define HD 128
#define SEQ 2048
#define EPS 1e-6f
#define SCALE 0.08838834764831845f  // 128^-0.5

typedef __attribute__((ext_vector_type(8))) short bf8_t;   // 8 bf16 (4 VGPRs)
typedef __attribute__((ext_vector_type(4))) float f4_t;    // 4 fp32

__device__ __forceinline__ short f2bf(float f) {
    union { __hip_bfloat16 h; short s; } u;
    u.h = __float2bfloat16(f);
    return u.s;
}
__device__ __forceinline__ float bf2f(short s) {
    union { short s; __hip_bfloat16 h; } u;
    u.s = s;
    return __bfloat162float(u.h);
}
__device__ __forceinline__ bf8_t pack8(const float4& a, const float4& b) {
    bf8_t r;
    r[0] = f2bf(a.x); r[1] = f2bf(a.y); r[2] = f2bf(a.z); r[3] = f2bf(a.w);
    r[4] = f2bf(b.x); r[5] = f2bf(b.y); r[6] = f2bf(b.z); r[7] = f2bf(b.w);
    return r;
}
// async global->LDS DMA, 16 B per lane; per-lane global addr, lds dest = base + lane*16
__device__ __forceinline__ void gload16(const short* g, short* l) {
    __builtin_amdgcn_global_load_lds(
        (const __attribute__((address_space(1))) unsigned int*)g,
        (__attribute__((address_space(3))) unsigned int*)l, 16, 0, 0);
}

__device__ __forceinline__ float wave_reduce_sum(float v) {
#pragma unroll
    for (int off = 32; off > 0; off >>= 1) v += __shfl_xor(v, off);
    return v;
}

// ---------------- fp32 -> bf16 convert (weights) ----------------
__global__ __launch_bounds__(256) void f2bf_kernel(
    const float* __restrict__ src, short* __restrict__ dst, int n8) {
    int i = blockIdx.x * 256 + threadIdx.x;
    if (i < n8) {
        float4 a = *(const float4*)(src + (size_t)i * 8);
        float4 b = *(const float4*)(src + (size_t)i * 8 + 4);
        *(bf8_t*)(dst + (size_t)i * 8) = pack8(a, b);
    }
}

// ---------------- 1. hidden RMSNorm (fp32 in, bf16 out) ----------------
__global__ __launch_bounds__(256) void rmsnorm_hid_kernel(
    const float* __restrict__ x, const float* __restrict__ w,
    short* __restrict__ out) {
    int row = blockIdx.x;
    int tid = threadIdx.x;
    const float* xr = x + (size_t)row * HID;
    float4 a = *(const float4*)(xr + tid * 8);
    float4 b = *(const float4*)(xr + tid * 8 + 4);
    float ss = a.x * a.x + a.y * a.y + a.z * a.z + a.w * a.w +
               b.x * b.x + b.y * b.y + b.z * b.z + b.w * b.w;
    ss = wave_reduce_sum(ss);
    __shared__ float part[4];
    __shared__ float s_scale;
    if ((tid & 63) == 0) part[tid >> 6] = ss;
    __syncthreads();
    if (tid == 0) {
        float t = part[0] + part[1] + part[2] + part[3];
        s_scale = rsqrtf(t / (float)HID + EPS);
    }
    __syncthreads();
    float sc = s_scale;
    float4 wa = *(const float4*)(w + tid * 8);
    float4 wb = *(const float4*)(w + tid * 8 + 4);
    float4 oa = make_float4(a.x * sc * wa.x, a.y * sc * wa.y,
                            a.z * sc * wa.z, a.w * sc * wa.w);
    float4 ob = make_float4(b.x * sc * wb.x, b.y * sc * wb.y,
                            b.z * sc * wb.z, b.w * sc * wb.w);
    *(bf8_t*)(out + (size_t)row * HID + tid * 8) = pack8(oa, ob);
}

// ---------------- 2/5. bf16 MFMA GEMM: C = A @ B^T, BK=64 ----------------
// 128x128 tile, 4 waves (2x2) x 64x64, mfma_f32_16x16x32_bf16.
// global_load_lds staging; unpadded LDS, slot = (chunk + row) & 7 XOR swizzle
// (16-lane b128 frag groups land 2-way on banks = free).
// MODE 0: fp32 store to Cf. MODE 1: qkv split -> Q bf16, Kp bf16, Vr bf16 ROW-major.
template <int MODE>
__global__ __launch_bounds__(256) void gemm_mfma_kernel(
    const short* __restrict__ A, const short* __restrict__ B,
    float* __restrict__ Cf, short* __restrict__ Q, short* __restrict__ Kp,
    short* __restrict__ Vr, int M, int N, int K) {
    __shared__ short As[128][64];
    __shared__ short Bs[128][64];
    int tid = threadIdx.x;
    int wv = tid >> 6, lane = tid & 63;
    int n16 = lane & 15, qd = lane >> 4;
    int m0 = blockIdx.y * 128, n0 = blockIdx.x * 128;
    int wm = (wv >> 1) * 64, wn = (wv & 1) * 64;
    int sr8 = lane >> 3, slot = lane & 7;

    size_t ainv[4], binv[4];
#pragma unroll
    for (int it = 0; it < 4; ++it) {
        int row = wv * 32 + it * 8 + sr8;
        int chunk = (slot - row) & 7;
        ainv[it] = (size_t)(m0 + row) * K + chunk * 8;
        binv[it] = (size_t)(n0 + row) * K + chunk * 8;
    }

    f4_t acc[4][4];
#pragma unroll
    for (int i = 0; i < 4; ++i)
#pragma unroll
        for (int j = 0; j < 4; ++j) acc[i][j] = (f4_t){0.f, 0.f, 0.f, 0.f};

    for (int k0 = 0; k0 < K; k0 += 64) {
        __syncthreads();
#pragma unroll
        for (int it = 0; it < 4; ++it) {
            gload16(A + ainv[it] + k0, &As[wv * 32 + it * 8][0]);
            gload16(B + binv[it] + k0, &Bs[wv * 32 + it * 8][0]);
        }
        __syncthreads();

        bf8_t af[4][2], bf[4][2];
#pragma unroll
        for (int t = 0; t < 4; ++t)
#pragma unroll
            for (int ks = 0; ks < 2; ++ks) {
                int ar = wm + t * 16 + n16;
                af[t][ks] = *(const bf8_t*)&As[ar][(((ks * 4 + qd) + ar) & 7) * 8];
                int br = wn + t * 16 + n16;
                bf[t][ks] = *(const bf8_t*)&Bs[br][(((ks * 4 + qd) + br) & 7) * 8];
            }
#pragma unroll
        for (int ks = 0; ks < 2; ++ks)
#pragma unroll
            for (int mt = 0; mt < 4; ++mt)
#pragma unroll
                for (int nt = 0; nt < 4; ++nt)
                    acc[mt][nt] = __builtin_amdgcn_mfma_f32_16x16x32_bf16(
                        af[mt][ks], bf[nt][ks], acc[mt][nt], 0, 0, 0);
    }

#pragma unroll
    for (int mt = 0; mt < 4; ++mt)
#pragma unroll
        for (int nt = 0; nt < 4; ++nt)
#pragma unroll
            for (int r = 0; r < 4; ++r) {
                int gm = m0 + wm + mt * 16 + qd * 4 + r;
                int gn = n0 + wn + nt * 16 + n16;
                float v = acc[mt][nt][r];
                if (MODE == 0) {
                    Cf[(size_t)gm * N + gn] = v;
                } else {
                    if (gn < NH * HD)
                        Q[(size_t)gm * (NH * HD) + gn] = f2bf(v);
                    else if (gn < (NH + NKV) * HD)
                        Kp[(size_t)gm * (NKV * HD) + (gn - NH * HD)] = f2bf(v);
                    else
                        Vr[(size_t)gm * (NKV * HD) + (gn - (NH + NKV) * HD)] = f2bf(v);
                }
            }
}

// ---------------- 2b. V row-major -> V^T (bf16), 64x64 LDS tiles ----------------
__global__ __launch_bounds__(256) void transpose_v_kernel(
    const short* __restrict__ vr, short* __restrict__ vt) {
    __shared__ short t[64][64];  // chunk-swizzled: chunk c of row s at slot (c+s)&7
    int s0 = blockIdx.x * 64, d0 = blockIdx.y * 64;
    int tid = threadIdx.x;
    int sl = tid >> 3, ch = tid & 7;
#pragma unroll
    for (int it = 0; it < 2; ++it) {
        int s_local = it * 32 + sl;
        bf8_t vv = *(const bf8_t*)(vr + (size_t)(s0 + s_local) * (NKV * HD) + d0 + ch * 8);
        *(bf8_t*)&t[s_local][((ch + s_local) & 7) * 8] = vv;
    }
    __syncthreads();
#pragma unroll
    for (int it = 0; it < 2; ++it) {
        int d_local = it * 32 + sl;
        int sbase = ch * 8;
        bf8_t o;
#pragma unroll
        for (int j = 0; j < 8; ++j) {
            int s = sbase + j;
            o[j] = t[s][(((d_local >> 3) + s) & 7) * 8 + (d_local & 7)];
        }
        *(bf8_t*)(vt + (size_t)(d0 + d_local) * SEQ + s0 + sbase) = o;
    }
}

// ---------------- 3. per-head q/k RMSNorm + RoPE (bf16, in place) ----------------
__global__ __launch_bounds__(128) void qknorm_rope_kernel(
    short* __restrict__ q, short* __restrict__ k,
    const float* __restrict__ qw, const float* __restrict__ kw,
    const int* __restrict__ pos) {
    int s = blockIdx.x;
    int hh = blockIdx.y;
    int d = threadIdx.x;
    short* ptr;
    const float* w;
    if (hh < NH) {
        ptr = q + (size_t)s * (NH * HD) + hh * HD;
        w = qw;
    } else {
        ptr = k + (size_t)s * (NKV * HD) + (hh - NH) * HD;
        w = kw;
    }
    float x = bf2f(ptr[d]);
    float ss = wave_reduce_sum(x * x);
    __shared__ float part[2];
    if ((d & 63) == 0) part[d >> 6] = ss;
    __syncthreads();
    float tot = part[0] + part[1];
    float xn = x * rsqrtf(tot / (float)HD + EPS) * w[d];
    __shared__ float sh[HD];
    sh[d] = xn;
    __syncthreads();
    int j = d & 63;
    float inv = powf(10000.0f, -(float)(2 * j) * (1.0f / (float)HD));
    float fr = (float)pos[s] * inv;
    float sn, cs;
    sincosf(fr, &sn, &cs);
    float o;
    if (d < 64)
        o = xn * cs - sh[d + 64] * sn;
    else
        o = xn * cs + sh[d - 64] * sn;
    ptr[d] = f2bf(o);
}

// ---------------- 4. MFMA flash attention v2 ----------------
// 128 threads = 2 waves; 64 q-rows/block (32/wave, 2 row-groups share K/V frags);
// 64-key tiles, double-buffered K/V via global_load_lds (separate A/B arrays so
// alias analysis can keep DMA uncounted against current-buffer ds_reads);
// ONE barrier per tile; P C->A round-trip via per-wave LDS (in-order LDS pipe).
__device__ __forceinline__ void attn_stage(
    short (&kb)[64][128], short (&vb)[128][64],
    const short* __restrict__ kg, const short* __restrict__ vg,
    int t0, const int (&kinv)[8], const int (&vinv)[8], int wv) {
#pragma unroll
    for (int it = 0; it < 8; ++it) {
        gload16(kg + (size_t)t0 * (NKV * HD) + kinv[it], &kb[wv * 32 + it * 4][0]);
        gload16(vg + t0 + vinv[it], &vb[wv * 64 + it * 8][0]);
    }
}

__device__ __forceinline__ void attn_tile(
    const short (&kb)[64][128], const short (&vb)[128][64],
    short (&psh)[2][2][16][72],
    const bf8_t (&qf)[2][4], f4_t (&of)[2][8],
    float (&m_i)[2][4], float (&l_p)[2][4],
    int wv, int n, int qd, bool diag) {
    f4_t sc[2][4];
#pragma unroll
    for (int g = 0; g < 2; ++g)
#pragma unroll
        for (int kk = 0; kk < 4; ++kk) sc[g][kk] = (f4_t){0.f, 0.f, 0.f, 0.f};
#pragma unroll
    for (int kk = 0; kk < 4; ++kk) {
        int key = kk * 16 + n;
#pragma unroll
        for (int ks = 0; ks < 4; ++ks) {
            bf8_t kf = *(const bf8_t*)&kb[key][(((ks * 4 + qd) + key) & 15) * 8];
            sc[0][kk] = __builtin_amdgcn_mfma_f32_16x16x32_bf16(qf[0][ks], kf, sc[0][kk], 0, 0, 0);
            sc[1][kk] = __builtin_amdgcn_mfma_f32_16x16x32_bf16(qf[1][ks], kf, sc[1][kk], 0, 0, 0);
        }
    }
#pragma unroll
    for (int g = 0; g < 2; ++g) {
        int rowb = wv * 32 + g * 16 + qd * 4;
#pragma unroll
        for (int kk = 0; kk < 4; ++kk)
#pragma unroll
            for (int r = 0; r < 4; ++r) {
                float s = sc[g][kk][r] * SCALE;
                if (diag && (kk * 16 + n > rowb + r)) s = -1e30f;
                sc[g][kk][r] = s;
            }
#pragma unroll
        for (int r = 0; r < 4; ++r) {
            float mx = fmaxf(fmaxf(sc[g][0][r], sc[g][1][r]),
                             fmaxf(sc[g][2][r], sc[g][3][r]));
#pragma unroll
            for (int off = 1; off < 16; off <<= 1) mx = fmaxf(mx, __shfl_xor(mx, off));
            float mnew = fmaxf(m_i[g][r], mx);
            float al = __expf(m_i[g][r] - mnew);
            m_i[g][r] = mnew;
            float lsum = 0.f;
#pragma unroll
            for (int kk = 0; kk < 4; ++kk) {
                float p = __expf(sc[g][kk][r] - mnew);
                psh[wv][g][qd * 4 + r][kk * 16 + n] = f2bf(p);
                lsum += p;
            }
            l_p[g][r] = l_p[g][r] * al + lsum;
#pragma unroll
            for (int nb = 0; nb < 8; ++nb) of[g][nb][r] *= al;
        }
    }
    __builtin_amdgcn_wave_barrier();  // keep psh writes above reads (same-wave, in-order LDS)
#pragma unroll
    for (int ks2 = 0; ks2 < 2; ++ks2) {
        bf8_t pf0 = *(const bf8_t*)&psh[wv][0][n][ks2 * 32 + qd * 8];
        bf8_t pf1 = *(const bf8_t*)&psh[wv][1][n][ks2 * 32 + qd * 8];
#pragma unroll
        for (int nb = 0; nb < 8; ++nb) {
            int dim = nb * 16 + n;
            bf8_t vf = *(const bf8_t*)&vb[dim][(((ks2 * 4 + qd) + dim) & 7) * 8];
            of[0][nb] = __builtin_amdgcn_mfma_f32_16x16x32_bf16(pf0, vf, of[0][nb], 0, 0, 0);
            of[1][nb] = __builtin_amdgcn_mfma_f32_16x16x32_bf16(pf1, vf, of[1][nb], 0, 0, 0);
        }
    }
}

__global__ __launch_bounds__(128) void attn_mfma_kernel(
    const short* __restrict__ q, const short* __restrict__ k,
    const short* __restrict__ vt, short* __restrict__ o) {
    __shared__ short kbufA[64][128], kbufB[64][128];
    __shared__ short vbufA[128][64], vbufB[128][64];
    __shared__ short psh[2][2][16][72];

    int tid = threadIdx.x;
    int wv = tid >> 6, lane = tid & 63;
    int n = lane & 15, qd = lane >> 4;
    int qb = (int)gridDim.x - 1 - (int)blockIdx.x;  // heavy blocks first
    int h = blockIdx.y, kvh = h >> 1;
    int qbase = qb * 64;

    // staging per-lane invariants (chunk-swizzled slots)
    int kinv[8], vinv[8];
#pragma unroll
    for (int it = 0; it < 8; ++it) {
        int key = wv * 32 + it * 4 + (lane >> 4);
        int ck = ((lane & 15) - key) & 15;
        kinv[it] = key * (NKV * HD) + kvh * HD + ck * 8;
        int dim = wv * 64 + it * 8 + (lane >> 3);
        int cv = ((lane & 7) - dim) & 7;
        vinv[it] = (kvh * HD + dim) * SEQ + cv * 8;
    }

    bf8_t qf[2][4];
#pragma unroll
    for (int g = 0; g < 2; ++g) {
        const short* qp =
            q + (size_t)(qbase + wv * 32 + g * 16 + n) * (NH * HD) + h * HD + qd * 8;
#pragma unroll
        for (int ks = 0; ks < 4; ++ks) qf[g][ks] = *(const bf8_t*)(qp + ks * 32);
    }

    f4_t of[2][8];
#pragma unroll
    for (int g = 0; g < 2; ++g)
#pragma unroll
        for (int i = 0; i < 8; ++i) of[g][i] = (f4_t){0.f, 0.f, 0.f, 0.f};
    float m_i[2][4] = {{-1e30f, -1e30f, -1e30f, -1e30f}, {-1e30f, -1e30f, -1e30f, -1e30f}};
    float l_p[2][4] = {{0.f, 0.f, 0.f, 0.f}, {0.f, 0.f, 0.f, 0.f}};

    int ntiles = qb + 1;
    attn_stage(kbufA, vbufA, k, vt, 0, kinv, vinv, wv);
    for (int tt = 0; tt < ntiles; tt += 2) {
        __syncthreads();  // drains DMA for tile tt (issued a full tile ago)
        if (tt + 1 < ntiles)
            attn_stage(kbufB, vbufB, k, vt, (tt + 1) * 64, kinv, vinv, wv);
        attn_tile(kbufA, vbufA, psh, qf, of, m_i, l_p, wv, n, qd, tt == qb);
        if (tt + 1 < ntiles) {
            __syncthreads();
            if (tt + 2 < ntiles)
                attn_stage(kbufA, vbufA, k, vt, (tt + 2) * 64, kinv, vinv, wv);
            attn_tile(kbufB, vbufB, psh, qf, of, m_i, l_p, wv, n, qd, tt + 1 == qb);
        }
    }

    float inv[2][4];
#pragma unroll
    for (int g = 0; g < 2; ++g)
#pragma unroll
        for (int r = 0; r < 4; ++r) {
            float l = l_p[g][r];
#pragma unroll
            for (int off = 1; off < 16; off <<= 1) l += __shfl_xor(l, off);
            inv[g][r] = 1.0f / l;
        }
#pragma unroll
    for (int g = 0; g < 2; ++g)
#pragma unroll
        for (int nb = 0; nb < 8; ++nb)
#pragma unroll
            for (int r = 0; r < 4; ++r) {
                int row = qbase + wv * 32 + g * 16 + qd * 4 + r;
                o[(size_t)row * (NH * HD) + h * HD + nb * 16 + n] =
                    f2bf(of[g][nb][r] * inv[g][r]);
            }
}

// ---------------- launch ----------------
extern "C" void kernel_launch(void* const* d_in, const int* in_sizes, int n_in,
                              void* d_out, int out_size, void* d_ws, size_t ws_size,
                              hipStream_t stream) {
    const int* positions   = (const int*)d_in[0];
    const float* hidden    = (const float*)d_in[1];
    const float* ln_w      = (const float*)d_in[2];
    const float* w_qkv     = (const float*)d_in[3];
    const float* w_o       = (const float*)d_in[4];
    const float* q_norm_w  = (const float*)d_in[5];
    const float* k_norm_w  = (const float*)d_in[6];
    float* out = (float*)d_out;

    char* base = (char*)d_ws;
    short* hnb  = (short*)(base);                       // 8 MB: hn bf16 -> attn-out bf16
    short* wqb  = (short*)(base + ((size_t)8 << 20));   // 16 MB: w_qkv bf16 (dead after QKV gemm)
    short* vtb  = (short*)(base + ((size_t)8 << 20));   // reuses wqb region after gemm
    short* wob  = (short*)(base + ((size_t)24 << 20));  // 8 MB: w_o bf16
    short* qbf  = (short*)(base + ((size_t)32 << 20));  // 8 MB: q bf16
    short* kbf  = (short*)(base + ((size_t)40 << 20));  // 4 MB: k bf16
    short* vrow = (short*)(base + ((size_t)44 << 20));  // 4 MB: v bf16 row-major

    f2bf_kernel<<<4096, 256, 0, stream>>>(w_qkv, wqb, (NH + 2 * NKV) * HD * HID / 8);
    f2bf_kernel<<<2048, 256, 0, stream>>>(w_o, wob, HID * NH * HD / 8);
    rmsnorm_hid_kernel<<<SEQ, 256, 0, stream>>>(hidden, ln_w, hnb);
    gemm_mfma_kernel<1><<<dim3(32, 16), 256, 0, stream>>>(
        hnb, wqb, nullptr, qbf, kbf, vrow, SEQ, (NH + 2 * NKV) * HD, HID);
    transpose_v_kernel<<<dim3(SEQ / 64, NKV * HD / 64), 256, 0, stream>>>(vrow, vtb);
    qknorm_rope_kernel<<<dim3(SEQ, NH + NKV), 128, 0, stream>>>(
        qbf, kbf, q_norm_w, k_norm_w, positions);
    attn_mfma_kernel<<<dim3(32, NH), 128, 0, stream>>>(qbf, kbf, vtb, hnb);
    gemm_mfma_kernel<0><<<dim3(16, 16), 256, 0, stream>>>(
        hnb, wob, out, nullptr, nullptr, nullptr, SEQ, NH * HD, HID);
}

// Round 5
// 293.029 us; speedup vs baseline: 7.8601x; 1.1344x over previous
//
#include <hip/hip_runtime.h>
#include <hip/hip_bf16.h>
#include <math.h>

#define HID 2048
#define NH 16
#define NKV 8
#define HD 128
#define SEQ 2048
#define EPS 1e-6f
#define SCALE 0.08838834764831845f  // 128^-0.5

typedef __attribute__((ext_vector_type(8))) short bf8_t;   // 8 bf16 (4 VGPRs)
typedef __attribute__((ext_vector_type(4))) float f4_t;    // 4 fp32

__device__ __forceinline__ short f2bf(float f) {
    union { __hip_bfloat16 h; short s; } u;
    u.h = __float2bfloat16(f);
    return u.s;
}
__device__ __forceinline__ float bf2f(short s) {
    union { short s; __hip_bfloat16 h; } u;
    u.s = s;
    return __bfloat162float(u.h);
}
__device__ __forceinline__ bf8_t pack8(const float4& a, const float4& b) {
    bf8_t r;
    r[0] = f2bf(a.x); r[1] = f2bf(a.y); r[2] = f2bf(a.z); r[3] = f2bf(a.w);
    r[4] = f2bf(b.x); r[5] = f2bf(b.y); r[6] = f2bf(b.z); r[7] = f2bf(b.w);
    return r;
}
// async global->LDS DMA, 16 B per lane; per-lane global addr, lds dest = base + lane*16
__device__ __forceinline__ void gload16(const short* g, short* l) {
    __builtin_amdgcn_global_load_lds(
        (const __attribute__((address_space(1))) unsigned int*)g,
        (__attribute__((address_space(3))) unsigned int*)l, 16, 0, 0);
}

__device__ __forceinline__ float wave_reduce_sum(float v) {
#pragma unroll
    for (int off = 32; off > 0; off >>= 1) v += __shfl_xor(v, off);
    return v;
}

// ---------------- fp32 -> bf16 convert (weights) ----------------
__global__ __launch_bounds__(256) void f2bf_kernel(
    const float* __restrict__ src, short* __restrict__ dst, int n8) {
    int i = blockIdx.x * 256 + threadIdx.x;
    if (i < n8) {
        float4 a = *(const float4*)(src + (size_t)i * 8);
        float4 b = *(const float4*)(src + (size_t)i * 8 + 4);
        *(bf8_t*)(dst + (size_t)i * 8) = pack8(a, b);
    }
}

// ---------------- 1. hidden RMSNorm (fp32 in, bf16 out) ----------------
__global__ __launch_bounds__(256) void rmsnorm_hid_kernel(
    const float* __restrict__ x, const float* __restrict__ w,
    short* __restrict__ out) {
    int row = blockIdx.x;
    int tid = threadIdx.x;
    const float* xr = x + (size_t)row * HID;
    float4 a = *(const float4*)(xr + tid * 8);
    float4 b = *(const float4*)(xr + tid * 8 + 4);
    float ss = a.x * a.x + a.y * a.y + a.z * a.z + a.w * a.w +
               b.x * b.x + b.y * b.y + b.z * b.z + b.w * b.w;
    ss = wave_reduce_sum(ss);
    __shared__ float part[4];
    __shared__ float s_scale;
    if ((tid & 63) == 0) part[tid >> 6] = ss;
    __syncthreads();
    if (tid == 0) {
        float t = part[0] + part[1] + part[2] + part[3];
        s_scale = rsqrtf(t / (float)HID + EPS);
    }
    __syncthreads();
    float sc = s_scale;
    float4 wa = *(const float4*)(w + tid * 8);
    float4 wb = *(const float4*)(w + tid * 8 + 4);
    float4 oa = make_float4(a.x * sc * wa.x, a.y * sc * wa.y,
                            a.z * sc * wa.z, a.w * sc * wa.w);
    float4 ob = make_float4(b.x * sc * wb.x, b.y * sc * wb.y,
                            b.z * sc * wb.z, b.w * sc * wb.w);
    *(bf8_t*)(out + (size_t)row * HID + tid * 8) = pack8(oa, ob);
}

// ---------------- 2/5. bf16 MFMA GEMM: C = A @ B^T, BK=64 ----------------
// 128x128 tile, 4 waves (2x2) x 64x64, mfma_f32_16x16x32_bf16.
// global_load_lds staging; unpadded LDS, slot = (chunk + row) & 7 XOR swizzle.
// MODE 0: fp32 store to Cf. MODE 1: qkv split -> Q bf16, Kp bf16, Vr bf16 ROW-major.
template <int MODE>
__global__ __launch_bounds__(256) void gemm_mfma_kernel(
    const short* __restrict__ A, const short* __restrict__ B,
    float* __restrict__ Cf, short* __restrict__ Q, short* __restrict__ Kp,
    short* __restrict__ Vr, int M, int N, int K) {
    __shared__ short As[128][64];
    __shared__ short Bs[128][64];
    int tid = threadIdx.x;
    int wv = tid >> 6, lane = tid & 63;
    int n16 = lane & 15, qd = lane >> 4;
    int m0 = blockIdx.y * 128, n0 = blockIdx.x * 128;
    int wm = (wv >> 1) * 64, wn = (wv & 1) * 64;
    int sr8 = lane >> 3, slot = lane & 7;

    size_t ainv[4], binv[4];
#pragma unroll
    for (int it = 0; it < 4; ++it) {
        int row = wv * 32 + it * 8 + sr8;
        int chunk = (slot - row) & 7;
        ainv[it] = (size_t)(m0 + row) * K + chunk * 8;
        binv[it] = (size_t)(n0 + row) * K + chunk * 8;
    }

    f4_t acc[4][4];
#pragma unroll
    for (int i = 0; i < 4; ++i)
#pragma unroll
        for (int j = 0; j < 4; ++j) acc[i][j] = (f4_t){0.f, 0.f, 0.f, 0.f};

    for (int k0 = 0; k0 < K; k0 += 64) {
        __syncthreads();
#pragma unroll
        for (int it = 0; it < 4; ++it) {
            gload16(A + ainv[it] + k0, &As[wv * 32 + it * 8][0]);
            gload16(B + binv[it] + k0, &Bs[wv * 32 + it * 8][0]);
        }
        __syncthreads();

        bf8_t af[4][2], bf[4][2];
#pragma unroll
        for (int t = 0; t < 4; ++t)
#pragma unroll
            for (int ks = 0; ks < 2; ++ks) {
                int ar = wm + t * 16 + n16;
                af[t][ks] = *(const bf8_t*)&As[ar][(((ks * 4 + qd) + ar) & 7) * 8];
                int br = wn + t * 16 + n16;
                bf[t][ks] = *(const bf8_t*)&Bs[br][(((ks * 4 + qd) + br) & 7) * 8];
            }
#pragma unroll
        for (int ks = 0; ks < 2; ++ks)
#pragma unroll
            for (int mt = 0; mt < 4; ++mt)
#pragma unroll
                for (int nt = 0; nt < 4; ++nt)
                    acc[mt][nt] = __builtin_amdgcn_mfma_f32_16x16x32_bf16(
                        af[mt][ks], bf[nt][ks], acc[mt][nt], 0, 0, 0);
    }

#pragma unroll
    for (int mt = 0; mt < 4; ++mt)
#pragma unroll
        for (int nt = 0; nt < 4; ++nt)
#pragma unroll
            for (int r = 0; r < 4; ++r) {
                int gm = m0 + wm + mt * 16 + qd * 4 + r;
                int gn = n0 + wn + nt * 16 + n16;
                float v = acc[mt][nt][r];
                if (MODE == 0) {
                    Cf[(size_t)gm * N + gn] = v;
                } else {
                    if (gn < NH * HD)
                        Q[(size_t)gm * (NH * HD) + gn] = f2bf(v);
                    else if (gn < (NH + NKV) * HD)
                        Kp[(size_t)gm * (NKV * HD) + (gn - NH * HD)] = f2bf(v);
                    else
                        Vr[(size_t)gm * (NKV * HD) + (gn - (NH + NKV) * HD)] = f2bf(v);
                }
            }
}

// ---------------- 2b. V row-major -> V^T (bf16), 64x64 LDS tiles ----------------
__global__ __launch_bounds__(256) void transpose_v_kernel(
    const short* __restrict__ vr, short* __restrict__ vt) {
    __shared__ short t[64][64];  // chunk-swizzled: chunk c of row s at slot (c+s)&7
    int s0 = blockIdx.x * 64, d0 = blockIdx.y * 64;
    int tid = threadIdx.x;
    int sl = tid >> 3, ch = tid & 7;
#pragma unroll
    for (int it = 0; it < 2; ++it) {
        int s_local = it * 32 + sl;
        bf8_t vv = *(const bf8_t*)(vr + (size_t)(s0 + s_local) * (NKV * HD) + d0 + ch * 8);
        *(bf8_t*)&t[s_local][((ch + s_local) & 7) * 8] = vv;
    }
    __syncthreads();
#pragma unroll
    for (int it = 0; it < 2; ++it) {
        int d_local = it * 32 + sl;
        int sbase = ch * 8;
        bf8_t o;
#pragma unroll
        for (int j = 0; j < 8; ++j) {
            int s = sbase + j;
            o[j] = t[s][(((d_local >> 3) + s) & 7) * 8 + (d_local & 7)];
        }
        *(bf8_t*)(vt + (size_t)(d0 + d_local) * SEQ + s0 + sbase) = o;
    }
}

// ---------------- 3. per-head q/k RMSNorm + RoPE (bf16, in place) ----------------
__global__ __launch_bounds__(128) void qknorm_rope_kernel(
    short* __restrict__ q, short* __restrict__ k,
    const float* __restrict__ qw, const float* __restrict__ kw,
    const int* __restrict__ pos) {
    int s = blockIdx.x;
    int hh = blockIdx.y;
    int d = threadIdx.x;
    short* ptr;
    const float* w;
    if (hh < NH) {
        ptr = q + (size_t)s * (NH * HD) + hh * HD;
        w = qw;
    } else {
        ptr = k + (size_t)s * (NKV * HD) + (hh - NH) * HD;
        w = kw;
    }
    float x = bf2f(ptr[d]);
    float ss = wave_reduce_sum(x * x);
    __shared__ float part[2];
    if ((d & 63) == 0) part[d >> 6] = ss;
    __syncthreads();
    float tot = part[0] + part[1];
    float xn = x * rsqrtf(tot / (float)HD + EPS) * w[d];
    __shared__ float sh[HD];
    sh[d] = xn;
    __syncthreads();
    int j = d & 63;
    float inv = powf(10000.0f, -(float)(2 * j) * (1.0f / (float)HD));
    float fr = (float)pos[s] * inv;
    float sn, cs;
    sincosf(fr, &sn, &cs);
    float o;
    if (d < 64)
        o = xn * cs - sh[d + 64] * sn;
    else
        o = xn * cs + sh[d - 64] * sn;
    ptr[d] = f2bf(o);
}

// ---------------- 4. MFMA flash attention v3 ----------------
// 256 threads = 4 waves; 64 q-rows/block (16/wave); 64-key tiles double-buffered
// via global_load_lds; ONE barrier per tile; P C->A round-trip via per-wave LDS.
// Anti-correlated (qb,h) mapping so co-resident block pairs have equal total work.
__device__ __forceinline__ void attn_stage(
    short (&kb)[64][128], short (&vb)[128][64],
    const short* __restrict__ kg, const short* __restrict__ vg,
    int t0, const int (&kinv)[4], const int (&vinv)[4], int wv) {
#pragma unroll
    for (int it = 0; it < 4; ++it) {
        gload16(kg + (size_t)t0 * (NKV * HD) + kinv[it], &kb[wv * 16 + it * 4][0]);
        gload16(vg + t0 + vinv[it], &vb[wv * 32 + it * 8][0]);
    }
}

__device__ __forceinline__ void attn_tile(
    const short (&kb)[64][128], const short (&vb)[128][64],
    short (&psh)[4][16][72],
    const bf8_t (&qf)[4], f4_t (&of)[8],
    float (&m_i)[4], float (&l_p)[4],
    int wv, int n, int qd, bool diag) {
    f4_t sc[4];
#pragma unroll
    for (int kk = 0; kk < 4; ++kk) sc[kk] = (f4_t){0.f, 0.f, 0.f, 0.f};
#pragma unroll
    for (int kk = 0; kk < 4; ++kk) {
        int key = kk * 16 + n;
#pragma unroll
        for (int ks = 0; ks < 4; ++ks) {
            bf8_t kf = *(const bf8_t*)&kb[key][(((ks * 4 + qd) + key) & 15) * 8];
            sc[kk] = __builtin_amdgcn_mfma_f32_16x16x32_bf16(qf[ks], kf, sc[kk], 0, 0, 0);
        }
    }
    int rowb = wv * 16 + qd * 4;
#pragma unroll
    for (int kk = 0; kk < 4; ++kk)
#pragma unroll
        for (int r = 0; r < 4; ++r) {
            float s = sc[kk][r] * SCALE;
            if (diag && (kk * 16 + n > rowb + r)) s = -1e30f;
            sc[kk][r] = s;
        }
#pragma unroll
    for (int r = 0; r < 4; ++r) {
        float mx = fmaxf(fmaxf(sc[0][r], sc[1][r]), fmaxf(sc[2][r], sc[3][r]));
#pragma unroll
        for (int off = 1; off < 16; off <<= 1) mx = fmaxf(mx, __shfl_xor(mx, off));
        float mnew = fmaxf(m_i[r], mx);
        float al = __expf(m_i[r] - mnew);
        m_i[r] = mnew;
        float lsum = 0.f;
#pragma unroll
        for (int kk = 0; kk < 4; ++kk) {
            float p = __expf(sc[kk][r] - mnew);
            psh[wv][qd * 4 + r][kk * 16 + n] = f2bf(p);
            lsum += p;
        }
        l_p[r] = l_p[r] * al + lsum;
#pragma unroll
        for (int nb = 0; nb < 8; ++nb) of[nb][r] *= al;
    }
    __builtin_amdgcn_wave_barrier();  // psh write->read same wave, in-order LDS
#pragma unroll
    for (int ks2 = 0; ks2 < 2; ++ks2) {
        bf8_t pf = *(const bf8_t*)&psh[wv][n][ks2 * 32 + qd * 8];
#pragma unroll
        for (int nb = 0; nb < 8; ++nb) {
            int dim = nb * 16 + n;
            bf8_t vf = *(const bf8_t*)&vb[dim][(((ks2 * 4 + qd) + dim) & 7) * 8];
            of[nb] = __builtin_amdgcn_mfma_f32_16x16x32_bf16(pf, vf, of[nb], 0, 0, 0);
        }
    }
}

__global__ __launch_bounds__(256) void attn_mfma_kernel(
    const short* __restrict__ q, const short* __restrict__ k,
    const short* __restrict__ vt, short* __restrict__ o) {
    __shared__ short kbufA[64][128], kbufB[64][128];
    __shared__ short vbufA[128][64], vbufB[128][64];
    __shared__ short psh[4][16][72];

    int tid = threadIdx.x;
    int wv = tid >> 6, lane = tid & 63;
    int n = lane & 15, qd = lane >> 4;
    // balance mapping: co-resident pair (bid, bid+256) -> qb sums to 31
    int bid = blockIdx.x;
    int p = bid & 255;
    int h, qb;
    if (bid < 256) { h = p >> 5;       qb = 31 - (p & 31); }
    else           { h = 8 + (p >> 5); qb = p & 31; }
    int kvh = h >> 1;
    int qbase = qb * 64;

    int kinv[4], vinv[4];
#pragma unroll
    for (int it = 0; it < 4; ++it) {
        int key = wv * 16 + it * 4 + (lane >> 4);
        int ck = ((lane & 15) - key) & 15;
        kinv[it] = key * (NKV * HD) + kvh * HD + ck * 8;
        int dim = wv * 32 + it * 8 + (lane >> 3);
        int cv = ((lane & 7) - dim) & 7;
        vinv[it] = (kvh * HD + dim) * SEQ + cv * 8;
    }

    bf8_t qf[4];
    {
        const short* qp = q + (size_t)(qbase + wv * 16 + n) * (NH * HD) + h * HD + qd * 8;
#pragma unroll
        for (int ks = 0; ks < 4; ++ks) qf[ks] = *(const bf8_t*)(qp + ks * 32);
    }

    f4_t of[8];
#pragma unroll
    for (int i = 0; i < 8; ++i) of[i] = (f4_t){0.f, 0.f, 0.f, 0.f};
    float m_i[4] = {-1e30f, -1e30f, -1e30f, -1e30f};
    float l_p[4] = {0.f, 0.f, 0.f, 0.f};

    int ntiles = qb + 1;
    attn_stage(kbufA, vbufA, k, vt, 0, kinv, vinv, wv);
    for (int tt = 0; tt < ntiles; tt += 2) {
        __syncthreads();  // drains DMA for tile tt (issued a full tile ago)
        if (tt + 1 < ntiles)
            attn_stage(kbufB, vbufB, k, vt, (tt + 1) * 64, kinv, vinv, wv);
        attn_tile(kbufA, vbufA, psh, qf, of, m_i, l_p, wv, n, qd, tt == qb);
        if (tt + 1 < ntiles) {
            __syncthreads();
            if (tt + 2 < ntiles)
                attn_stage(kbufA, vbufA, k, vt, (tt + 2) * 64, kinv, vinv, wv);
            attn_tile(kbufB, vbufB, psh, qf, of, m_i, l_p, wv, n, qd, tt + 1 == qb);
        }
    }

    float inv[4];
#pragma unroll
    for (int r = 0; r < 4; ++r) {
        float l = l_p[r];
#pragma unroll
        for (int off = 1; off < 16; off <<= 1) l += __shfl_xor(l, off);
        inv[r] = 1.0f / l;
    }
#pragma unroll
    for (int nb = 0; nb < 8; ++nb)
#pragma unroll
        for (int r = 0; r < 4; ++r) {
            int row = qbase + wv * 16 + qd * 4 + r;
            o[(size_t)row * (NH * HD) + h * HD + nb * 16 + n] = f2bf(of[nb][r] * inv[r]);
        }
}

// ---------------- launch ----------------
extern "C" void kernel_launch(void* const* d_in, const int* in_sizes, int n_in,
                              void* d_out, int out_size, void* d_ws, size_t ws_size,
                              hipStream_t stream) {
    const int* positions   = (const int*)d_in[0];
    const float* hidden    = (const float*)d_in[1];
    const float* ln_w      = (const float*)d_in[2];
    const float* w_qkv     = (const float*)d_in[3];
    const float* w_o       = (const float*)d_in[4];
    const float* q_norm_w  = (const float*)d_in[5];
    const float* k_norm_w  = (const float*)d_in[6];
    float* out = (float*)d_out;

    char* base = (char*)d_ws;
    short* hnb  = (short*)(base);                       // 8 MB: hn bf16 -> attn-out bf16
    short* wqb  = (short*)(base + ((size_t)8 << 20));   // 16 MB: w_qkv bf16 (dead after QKV gemm)
    short* vtb  = (short*)(base + ((size_t)8 << 20));   // reuses wqb region after gemm
    short* wob  = (short*)(base + ((size_t)24 << 20));  // 8 MB: w_o bf16
    short* qbf  = (short*)(base + ((size_t)32 << 20));  // 8 MB: q bf16
    short* kbf  = (short*)(base + ((size_t)40 << 20));  // 4 MB: k bf16
    short* vrow = (short*)(base + ((size_t)44 << 20));  // 4 MB: v bf16 row-major

    f2bf_kernel<<<4096, 256, 0, stream>>>(w_qkv, wqb, (NH + 2 * NKV) * HD * HID / 8);
    f2bf_kernel<<<2048, 256, 0, stream>>>(w_o, wob, HID * NH * HD / 8);
    rmsnorm_hid_kernel<<<SEQ, 256, 0, stream>>>(hidden, ln_w, hnb);
    gemm_mfma_kernel<1><<<dim3(32, 16), 256, 0, stream>>>(
        hnb, wqb, nullptr, qbf, kbf, vrow, SEQ, (NH + 2 * NKV) * HD, HID);
    transpose_v_kernel<<<dim3(SEQ / 64, NKV * HD / 64), 256, 0, stream>>>(vrow, vtb);
    qknorm_rope_kernel<<<dim3(SEQ, NH + NKV), 128, 0, stream>>>(
        qbf, kbf, q_norm_w, k_norm_w, positions);
    attn_mfma_kernel<<<512, 256, 0, stream>>>(qbf, kbf, vtb, hnb);
    gemm_mfma_kernel<0><<<dim3(16, 16), 256, 0, stream>>>(
        hnb, wob, out, nullptr, nullptr, nullptr, SEQ, NH * HD, HID);
}